// Round 3
// baseline (61919.196 us; speedup 1.0000x reference)
//
#include <hip/hip_runtime.h>

// Problem constants
#define SEQ   8192
#define VOCAB 256
#define HID   2048
#define ODIM  256
#define NBLK  256   // persistent blocks (1 per CU)
#define NTHR  512   // 8 waves per block
#define JPB   8     // hidden columns owned per block (HID/NBLK)

// Fast gate math: v_exp_f32 + v_rcp_f32 (~1ulp each; threshold is bf16-scale)
__device__ __forceinline__ float fsigmoid(float x) {
    return __builtin_amdgcn_rcpf(1.f + __expf(-x));
}
__device__ __forceinline__ float ftanh(float x) {
    x = fminf(20.f, fmaxf(-20.f, x));                 // avoid inf*0 NaN
    float e = __expf(2.f * x);
    return (e - 1.f) * __builtin_amdgcn_rcpf(e + 1.f);
}

// ---------------------------------------------------------------------------
// K1: Zv[v][gate][j] = emb[v] @ W_gate[:,j] + b_gate[j] + c_gate[j]
// 256 distinct x values -> whole input projection is an 8 MB lookup table.
// ---------------------------------------------------------------------------
__global__ void k_zv(const float* __restrict__ emb, const float* __restrict__ W,
                     const float* __restrict__ bb, const float* __restrict__ cb,
                     float* __restrict__ Zv, int gate) {
    __shared__ float e[32][VOCAB];
    const int tid = threadIdx.x;
    const int vt = blockIdx.x, ct = blockIdx.y;
    for (int r = 0; r < 32; ++r)
        e[r][tid] = emb[(size_t)(vt * 32 + r) * VOCAB + tid];
    __syncthreads();
    const int j = ct * 256 + tid;
    const float bias = bb[j] + cb[j];
    float acc[32];
#pragma unroll
    for (int r = 0; r < 32; ++r) acc[r] = 0.f;
    for (int u = 0; u < VOCAB; ++u) {
        float w = W[(size_t)u * HID + j];
#pragma unroll
        for (int r = 0; r < 32; ++r) acc[r] += e[r][u] * w;
    }
    for (int r = 0; r < 32; ++r)
        Zv[(size_t)(vt * 32 + r) * (4 * HID) + (size_t)gate * HID + j] = acc[r] + bias;
}

// ---------------------------------------------------------------------------
// K2: persistent cooperative LSTM.
// Exchange protocol per step t (consumer side, thread = (gate, rs)):
//   1) hot-spin on epoch HINTS of its own 2 producers (2 x 4B; 1 KB/block/iter
//      at the LLC -- 16x less poll traffic than a full pair cover)
//   2) single direct read of its 16 (h,epoch) pairs -> registers; pair epochs
//      are authoritative, re-read on mismatch (hint/data stores unordered)
//   3) register matvec 16x8, butterfly reduce, ONE __syncthreads
//      (scr2 parity-double-buffered), wave0 gates, publish pairs then hint.
// No LDS h staging, no pre-matvec barrier, no s_sleep quantization.
// ---------------------------------------------------------------------------
__launch_bounds__(NTHR, 2)
__global__ void k_lstm(const float* __restrict__ Uii, const float* __restrict__ Uff,
                       const float* __restrict__ Ugg, const float* __restrict__ Uoo,
                       const float* __restrict__ Zv,  const int* __restrict__ x,
                       unsigned long long* pub, unsigned* hint,
                       float* __restrict__ hs, float* __restrict__ outTail) {
    __shared__ __align__(16) float scr2[2][8 * 32];  // parity-buffered wave sums

    const int tid  = threadIdx.x;
    const int b    = blockIdx.x;
    const int gate = tid & 3;
    const int rs   = tid >> 2;              // 0..127: rows [16rs,16rs+16)
    const int lane = tid & 63;
    const int wv   = tid >> 6;

    const float* Ug = (gate == 0) ? Uii : (gate == 1) ? Uff : (gate == 2) ? Ugg : Uoo;

    // U slice -> registers (rows rs*16..+16, cols 8b..8b+8) = 128 f32/thread
    float u[16][JPB];
#pragma unroll
    for (int r = 0; r < 16; ++r) {
        const float4* p = (const float4*)(Ug + (size_t)(rs * 16 + r) * HID + b * JPB);
        float4 a0 = p[0], a1 = p[1];
        u[r][0] = a0.x; u[r][1] = a0.y; u[r][2] = a0.z; u[r][3] = a0.w;
        u[r][4] = a1.x; u[r][5] = a1.y; u[r][6] = a1.z; u[r][7] = a1.w;
    }

    float creg = 0.f;                       // cell state, wave0 lanes 0-7
    unsigned budget = 1u << 22;             // watchdog: bounded spin, fails loudly

    for (int t = 0; t < SEQ; ++t) {
        // Zv prefetch (independent of h; overlaps the spin)
        float zx = 0.f;
        if (wv == 0 && lane < 32) {
            const int xt = x[t];
            zx = Zv[(size_t)xt * (4 * HID) + (size_t)(lane >> 3) * HID + b * JPB + (lane & 7)];
        }

        // Acquire this thread's 16 h values (rows 16rs..16rs+16)
        float hv[16];
        if (t == 0) {
#pragma unroll
            for (int k = 0; k < 16; ++k) hv[k] = 0.f;
        } else {
            const unsigned tgt = (unsigned)t;
            // 1) hint spin: 2 producers (p=2rs, 2rs+1)
            const unsigned* hp = hint + (size_t)(t & 1) * NBLK + rs * 2;
            for (;;) {
                unsigned h0 = __hip_atomic_load(hp,     __ATOMIC_RELAXED, __HIP_MEMORY_SCOPE_AGENT);
                unsigned h1 = __hip_atomic_load(hp + 1, __ATOMIC_RELAXED, __HIP_MEMORY_SCOPE_AGENT);
                if ((h0 == tgt && h1 == tgt) || budget == 0) break;
                --budget;
            }
            // 2) direct pair read, epoch-verified (authoritative)
            const unsigned long long* sl = pub + (size_t)(t & 1) * HID + rs * 16;
            for (;;) {
                unsigned long long a[16];
#pragma unroll
                for (int k = 0; k < 16; ++k)
                    a[k] = __hip_atomic_load(sl + k, __ATOMIC_RELAXED, __HIP_MEMORY_SCOPE_AGENT);
                bool ok = true;
#pragma unroll
                for (int k = 0; k < 16; ++k) ok &= ((unsigned)(a[k] >> 32) == tgt);
                if (ok || budget == 0) {
#pragma unroll
                    for (int k = 0; k < 16; ++k) hv[k] = __uint_as_float((unsigned)a[k]);
                    break;
                }
                --budget;
            }
        }

        // Register matvec: 16 rows x 8 cols
        float acc[JPB];
#pragma unroll
        for (int jj = 0; jj < JPB; ++jj) acc[jj] = 0.f;
#pragma unroll
        for (int k = 0; k < 16; ++k)
#pragma unroll
            for (int jj = 0; jj < JPB; ++jj)
                acc[jj] += hv[k] * u[k][jj];

        // In-wave butterfly over rs bits (gate preserved in lane bits 0-1)
#pragma unroll
        for (int m = 4; m <= 32; m <<= 1)
#pragma unroll
            for (int jj = 0; jj < JPB; ++jj)
                acc[jj] += __shfl_xor(acc[jj], m, 64);
        if (lane < 4) {                     // lane==gate holds this wave's sums
            float4* p = (float4*)&scr2[t & 1][wv * 32 + lane * 8];
            p[0] = make_float4(acc[0], acc[1], acc[2], acc[3]);
            p[1] = make_float4(acc[4], acc[5], acc[6], acc[7]);
        }
        __syncthreads();                    // the ONLY barrier per step

        // wave0: cross-wave reduce + gates + publish (others run ahead)
        if (wv == 0) {
            float z = 0.f;
            if (lane < 32) {
#pragma unroll
                for (int w = 0; w < 8; ++w) z += scr2[t & 1][w * 32 + lane];
                z += zx;
            }
            const int jj = lane & 7;
            float zi = __shfl(z, jj);
            float zf = __shfl(z, 8 + jj);
            float zg = __shfl(z, 16 + jj);
            float zo = __shfl(z, 24 + jj);
            if (lane < JPB) {
                float ig = fsigmoid(zi);
                float fg = fsigmoid(zf);
                float gg = ftanh(zg);
                float og = fsigmoid(zo);
                float cn = fg * creg + ig * gg;
                float hn = og * ftanh(cn);
                creg = cn;
                const int jg = b * JPB + lane;
                // publish FIRST (critical path), then hint, then bulk stores
                unsigned long long pk =
                    ((unsigned long long)(unsigned)(t + 1) << 32) | __float_as_uint(hn);
                __hip_atomic_store(&pub[(size_t)((t + 1) & 1) * HID + jg], pk,
                                   __ATOMIC_RELAXED, __HIP_MEMORY_SCOPE_AGENT);
                if (lane == 0)
                    __hip_atomic_store(&hint[(size_t)((t + 1) & 1) * NBLK + b],
                                       (unsigned)(t + 1),
                                       __ATOMIC_RELAXED, __HIP_MEMORY_SCOPE_AGENT);
                hs[(size_t)t * HID + jg] = hn;
                if (t == SEQ - 1) { outTail[jg] = hn; outTail[HID + jg] = cn; }
            }
        }
    }
}

// ---------------------------------------------------------------------------
// K3: out[t][o] = hs[t] @ V_w[:,o] + V_b[o].
// ---------------------------------------------------------------------------
__global__ void k_out(const float* __restrict__ hs, const float* __restrict__ Vw,
                      const float* __restrict__ Vb, float* __restrict__ out) {
    __shared__ float tile[32][64];
    const int tid = threadIdx.x;
    const int t0 = blockIdx.x * 32;
    float acc[32];
#pragma unroll
    for (int r = 0; r < 32; ++r) acc[r] = 0.f;
    for (int k0 = 0; k0 < HID; k0 += 64) {
        {
            const int r = tid >> 3, kk = (tid & 7) * 8;
            const float4* p = (const float4*)(hs + (size_t)(t0 + r) * HID + k0 + kk);
            float4 a = p[0], bq = p[1];
            *(float4*)&tile[r][kk]     = a;
            *(float4*)&tile[r][kk + 4] = bq;
        }
        __syncthreads();
        for (int kk = 0; kk < 64; ++kk) {
            float w = Vw[(size_t)(k0 + kk) * ODIM + tid];
#pragma unroll
            for (int r = 0; r < 32; ++r) acc[r] += tile[r][kk] * w;
        }
        __syncthreads();
    }
    const float vb = Vb[tid];
    for (int r = 0; r < 32; ++r)
        out[(size_t)(t0 + r) * ODIM + tid] = acc[r] + vb;
}

// ---------------------------------------------------------------------------
extern "C" void kernel_launch(void* const* d_in, const int* in_sizes, int n_in,
                              void* d_out, int out_size, void* d_ws, size_t ws_size,
                              hipStream_t stream) {
    const int*   x   = (const int*)d_in[0];
    const float* emb = (const float*)d_in[1];
    const float* W[4] = {(const float*)d_in[2], (const float*)d_in[6],
                         (const float*)d_in[10], (const float*)d_in[14]};
    const float* B[4] = {(const float*)d_in[3], (const float*)d_in[7],
                         (const float*)d_in[11], (const float*)d_in[15]};
    const float* U[4] = {(const float*)d_in[4], (const float*)d_in[8],
                         (const float*)d_in[12], (const float*)d_in[16]};
    const float* C[4] = {(const float*)d_in[5], (const float*)d_in[9],
                         (const float*)d_in[13], (const float*)d_in[17]};
    const float* Vw = (const float*)d_in[18];
    const float* Vb = (const float*)d_in[19];
    float* out = (float*)d_out;

    // ws layout (floats): Zv[256*4*2048] | hs[8192*2048] | pub[2*2048 ull] |
    // hint[2*256 u32]. Poison 0xAAAAAAAA never equals a live epoch (1..8192),
    // and ws is re-poisoned before every timed call -> no init kernel needed.
    float* ws = (float*)d_ws;
    float* Zv = ws;
    float* hs = Zv + (size_t)VOCAB * 4 * HID;
    unsigned long long* pub = (unsigned long long*)(hs + (size_t)SEQ * HID);
    unsigned* hint = (unsigned*)(pub + 2 * HID);

    for (int g = 0; g < 4; ++g)
        k_zv<<<dim3(8, 8), dim3(256), 0, stream>>>(emb, W[g], B[g], C[g], Zv, g);

    float* outTail = out + (size_t)SEQ * ODIM;
    const float *Ui = U[0], *Uf = U[1], *Ugp = U[2], *Uo = U[3];
    const float* Zvc = Zv; const int* xc = x;
    unsigned long long* pubc = pub; unsigned* hintc = hint;
    float* hsc = hs; float* ot = outTail;
    void* args[10] = {&Ui, &Uf, &Ugp, &Uo, &Zvc, &xc, &pubc, &hintc, &hsc, &ot};
    hipLaunchCooperativeKernel((void*)k_lstm, dim3(NBLK), dim3(NTHR), args, 0, stream);

    k_out<<<dim3(256), dim3(256), 0, stream>>>(hs, Vw, Vb, out);
}

// Round 4
// 37723.563 us; speedup vs baseline: 1.6414x; 1.6414x over previous
//
#include <hip/hip_runtime.h>

// Problem constants
#define SEQ   8192
#define VOCAB 256
#define HID   2048
#define ODIM  256
#define NBLK  256   // persistent blocks (1 per CU)
#define NTHR  512   // 8 waves per block
#define JPB   8     // hidden columns owned per block (HID/NBLK)

typedef unsigned int v4u __attribute__((ext_vector_type(4)));

// sc0 = L1-bypass, L2-coherent (intra-XCD). NOT agent-coherent -- used only
// for the relay->sibling hop where both sides share one XCD L2, with an
// epoch-verified fallback to the sc1 (MALL) path if that assumption breaks.
__device__ __forceinline__ v4u load16_sc0(const void* p) {
    v4u r;
    asm volatile("global_load_dwordx4 %0, %1, off sc0\n\ts_waitcnt vmcnt(0)"
                 : "=v"(r) : "v"(p) : "memory");
    return r;
}
__device__ __forceinline__ void store16_sc0(void* p, v4u v) {
    asm volatile("global_store_dwordx4 %0, %1, off sc0" :: "v"(p), "v"(v) : "memory");
}

// Fast gate math: v_exp_f32 + v_rcp_f32 (~1ulp each; threshold is bf16-scale)
__device__ __forceinline__ float fsigmoid(float x) {
    return __builtin_amdgcn_rcpf(1.f + __expf(-x));
}
__device__ __forceinline__ float ftanh(float x) {
    x = fminf(20.f, fmaxf(-20.f, x));                 // avoid inf*0 NaN
    float e = __expf(2.f * x);
    return (e - 1.f) * __builtin_amdgcn_rcpf(e + 1.f);
}

// ---------------------------------------------------------------------------
// K0: zero the relay-election counters (ws is poisoned before every call).
// ---------------------------------------------------------------------------
__global__ void k_init(unsigned* cnt) {
    if (threadIdx.x < 32) cnt[threadIdx.x] = 0u;
}

// ---------------------------------------------------------------------------
// K1: Zv[v][gate][j] = emb[v] @ W_gate[:,j] + b_gate[j] + c_gate[j]
// 256 distinct x values -> whole input projection is an 8 MB lookup table.
// ---------------------------------------------------------------------------
__global__ void k_zv(const float* __restrict__ emb, const float* __restrict__ W,
                     const float* __restrict__ bb, const float* __restrict__ cb,
                     float* __restrict__ Zv, int gate) {
    __shared__ float e[32][VOCAB];
    const int tid = threadIdx.x;
    const int vt = blockIdx.x, ct = blockIdx.y;
    for (int r = 0; r < 32; ++r)
        e[r][tid] = emb[(size_t)(vt * 32 + r) * VOCAB + tid];
    __syncthreads();
    const int j = ct * 256 + tid;
    const float bias = bb[j] + cb[j];
    float acc[32];
#pragma unroll
    for (int r = 0; r < 32; ++r) acc[r] = 0.f;
    for (int u = 0; u < VOCAB; ++u) {
        float w = W[(size_t)u * HID + j];
#pragma unroll
        for (int r = 0; r < 32; ++r) acc[r] += e[r][u] * w;
    }
    for (int r = 0; r < 32; ++r)
        Zv[(size_t)(vt * 32 + r) * (4 * HID) + (size_t)gate * HID + j] = acc[r] + bias;
}

// ---------------------------------------------------------------------------
// K2: persistent cooperative LSTM with a per-XCD relay tree.
//   producers (wave0 lanes 0-7 of every block): publish (h,epoch) 8B pairs
//     into pub[] at AGENT scope (MALL), double-buffered by step parity.
//   relays (1 elected block per XCD): spin on pub at MALL -- only 8 blocks
//     generate MALL poll traffic (32x less than R2) -- then republish pairs
//     verbatim into an XCD-local buffer with sc0 stores (lands in own L2).
//   siblings: spin on the local buffer with sc0 loads (XCD-L2 hits, zero
//     MALL traffic). Epochs ride with the data, so no store ordering is
//     needed anywhere. If the local path doesn't go fresh within 256 rounds
//     (mis-grouped XCD id, cross-XCD staleness), the thread permanently
//     falls back to the proven R2 sc1 spin -- correctness never depends on
//     the relay path.
// Compute per step is exactly R2: LDS-stage h, register matvec (U resident,
// 128 f32/thread), butterfly reduce, wave0 gates + publish.
// ---------------------------------------------------------------------------
__launch_bounds__(NTHR, 2)
__global__ void k_lstm(const float* __restrict__ Uii, const float* __restrict__ Uff,
                       const float* __restrict__ Ugg, const float* __restrict__ Uoo,
                       const float* __restrict__ Zv,  const int* __restrict__ x,
                       unsigned long long* pub, unsigned long long* locb,
                       unsigned* cnt, float* __restrict__ hs,
                       float* __restrict__ outTail) {
    __shared__ __align__(16) float hpad[128 * 20];   // 10 KB padded h
    __shared__ __align__(16) float scr2[8 * 32];     // per-wave per-gate sums
    __shared__ int sh_x, sh_r;

    const int tid  = threadIdx.x;
    const int b    = blockIdx.x;
    const int gate = tid & 3;
    const int rs   = tid >> 2;              // 0..127: rows [16rs,16rs+16)
    const int lane = tid & 63;
    const int wv   = tid >> 6;

    // --- relay election: first block to claim each physical XCD ------------
    if (tid == 0) {
        unsigned xid = ((unsigned)__builtin_amdgcn_s_getreg(6164)) & 7u; // HW_REG_XCC_ID[3:0], size 4
        unsigned prev = atomicAdd(&cnt[xid], 1u);    // device-scope
        sh_x = (int)xid;
        sh_r = (prev == 0u) ? 1 : 0;
    }

    const float* Ug = (gate == 0) ? Uii : (gate == 1) ? Uff : (gate == 2) ? Ugg : Uoo;

    // U slice -> registers (rows rs*16..+16, cols 8b..8b+8) = 128 f32/thread
    float u[16][JPB];
#pragma unroll
    for (int r = 0; r < 16; ++r) {
        const float4* p = (const float4*)(Ug + (size_t)(rs * 16 + r) * HID + b * JPB);
        float4 a0 = p[0], a1 = p[1];
        u[r][0] = a0.x; u[r][1] = a0.y; u[r][2] = a0.z; u[r][3] = a0.w;
        u[r][4] = a1.x; u[r][5] = a1.y; u[r][6] = a1.z; u[r][7] = a1.w;
    }
    __syncthreads();
    const int  myx     = sh_x;
    const bool isRelay = (sh_r != 0);

    float4* hp4 = (float4*)hpad;
    float creg = 0.f;                       // cell state, wave0 lanes 0-7
    bool useLocal = !isRelay;
    unsigned budget = 1u << 22;             // watchdog: bounded spin, fails loudly

    for (int t = 0; t < SEQ; ++t) {
        // Zv prefetch (independent of h; overlaps the spin)
        float zx = 0.f;
        if (wv == 0 && lane < 32) {
            const int xt = x[t];
            zx = Zv[(size_t)xt * (4 * HID) + (size_t)(lane >> 3) * HID + b * JPB + (lane & 7)];
        }

        // --- acquire this thread's 4 h cols [4tid, 4tid+4) -----------------
        float4 hv;
        if (t == 0) {
            hv = make_float4(0.f, 0.f, 0.f, 0.f);
        } else {
            const unsigned tgt  = (unsigned)t;
            const size_t   slot = (size_t)(t & 1);
            unsigned long long* lp = locb + ((size_t)myx * 2 + slot) * HID + tid * 4;

            if (isRelay) {
                // MALL spin (only 8 blocks do this)
                const unsigned long long* sl = pub + slot * HID + tid * 4;
                unsigned long long a0, a1, a2, a3;
                for (;;) {
                    a0 = __hip_atomic_load(sl + 0, __ATOMIC_RELAXED, __HIP_MEMORY_SCOPE_AGENT);
                    a1 = __hip_atomic_load(sl + 1, __ATOMIC_RELAXED, __HIP_MEMORY_SCOPE_AGENT);
                    a2 = __hip_atomic_load(sl + 2, __ATOMIC_RELAXED, __HIP_MEMORY_SCOPE_AGENT);
                    a3 = __hip_atomic_load(sl + 3, __ATOMIC_RELAXED, __HIP_MEMORY_SCOPE_AGENT);
                    if (((unsigned)(a0 >> 32) == tgt) && ((unsigned)(a1 >> 32) == tgt) &&
                        ((unsigned)(a2 >> 32) == tgt) && ((unsigned)(a3 >> 32) == tgt)) break;
                    if (budget == 0) break;
                    --budget;
                }
                // republish verbatim into the XCD-local buffer (epoch rides along)
                v4u w0 = {(unsigned)a0, (unsigned)(a0 >> 32), (unsigned)a1, (unsigned)(a1 >> 32)};
                v4u w1 = {(unsigned)a2, (unsigned)(a2 >> 32), (unsigned)a3, (unsigned)(a3 >> 32)};
                store16_sc0(lp,     w0);
                store16_sc0(lp + 2, w1);
                hv.x = __uint_as_float((unsigned)a0);
                hv.y = __uint_as_float((unsigned)a1);
                hv.z = __uint_as_float((unsigned)a2);
                hv.w = __uint_as_float((unsigned)a3);
            } else {
                bool got = false;
                if (useLocal) {
                    for (int s = 0; s < 256; ++s) {
                        v4u A = load16_sc0(lp);
                        v4u B = load16_sc0(lp + 2);
                        if (A.y == tgt && A.w == tgt && B.y == tgt && B.w == tgt) {
                            hv.x = __uint_as_float(A.x);
                            hv.y = __uint_as_float(A.z);
                            hv.z = __uint_as_float(B.x);
                            hv.w = __uint_as_float(B.z);
                            got = true;
                            break;
                        }
                    }
                    if (!got) useLocal = false;   // local path broken: permanent sc1 fallback
                }
                if (!got) {
                    const unsigned long long* sl = pub + slot * HID + tid * 4;
                    unsigned long long a0, a1, a2, a3;
                    for (;;) {
                        a0 = __hip_atomic_load(sl + 0, __ATOMIC_RELAXED, __HIP_MEMORY_SCOPE_AGENT);
                        a1 = __hip_atomic_load(sl + 1, __ATOMIC_RELAXED, __HIP_MEMORY_SCOPE_AGENT);
                        a2 = __hip_atomic_load(sl + 2, __ATOMIC_RELAXED, __HIP_MEMORY_SCOPE_AGENT);
                        a3 = __hip_atomic_load(sl + 3, __ATOMIC_RELAXED, __HIP_MEMORY_SCOPE_AGENT);
                        if (((unsigned)(a0 >> 32) == tgt) && ((unsigned)(a1 >> 32) == tgt) &&
                            ((unsigned)(a2 >> 32) == tgt) && ((unsigned)(a3 >> 32) == tgt)) break;
                        if (budget == 0) break;
                        --budget;
                        __builtin_amdgcn_s_sleep(1);
                    }
                    hv.x = __uint_as_float((unsigned)a0);
                    hv.y = __uint_as_float((unsigned)a1);
                    hv.z = __uint_as_float((unsigned)a2);
                    hv.w = __uint_as_float((unsigned)a3);
                }
            }
        }

        // h cols [4tid, 4tid+4) -> padded LDS
        *(float4*)&hpad[(tid >> 2) * 20 + (tid & 3) * 4] = hv;
        __syncthreads();

        // --- register matvec: 16 rows x 8 cols per thread ------------------
        float acc[JPB];
#pragma unroll
        for (int jj = 0; jj < JPB; ++jj) acc[jj] = 0.f;
#pragma unroll
        for (int k = 0; k < 4; ++k) {
            float4 h4 = hp4[rs * 5 + k];
            float hvv[4] = {h4.x, h4.y, h4.z, h4.w};
#pragma unroll
            for (int i = 0; i < 4; ++i)
#pragma unroll
                for (int jj = 0; jj < JPB; ++jj)
                    acc[jj] += hvv[i] * u[k * 4 + i][jj];
        }

        // In-wave butterfly over rs bits (gate preserved in lane bits 0-1)
#pragma unroll
        for (int m = 4; m <= 32; m <<= 1)
#pragma unroll
            for (int jj = 0; jj < JPB; ++jj)
                acc[jj] += __shfl_xor(acc[jj], m, 64);
        if (lane < 4) {                     // lane==gate holds this wave's sums
            float4* p = (float4*)&scr2[wv * 32 + lane * 8];
            p[0] = make_float4(acc[0], acc[1], acc[2], acc[3]);
            p[1] = make_float4(acc[4], acc[5], acc[6], acc[7]);
        }
        __syncthreads();

        // --- wave0: cross-wave reduce + gates + publish --------------------
        if (wv == 0) {
            float z = 0.f;
            if (lane < 32) {
#pragma unroll
                for (int w = 0; w < 8; ++w) z += scr2[w * 32 + lane];
                z += zx;
            }
            const int jj = lane & 7;
            float zi = __shfl(z, jj);
            float zf = __shfl(z, 8 + jj);
            float zg = __shfl(z, 16 + jj);
            float zo = __shfl(z, 24 + jj);
            if (lane < JPB) {
                float ig = fsigmoid(zi);
                float fg = fsigmoid(zf);
                float gg = ftanh(zg);
                float og = fsigmoid(zo);
                float cn = fg * creg + ig * gg;
                float hn = og * ftanh(cn);
                creg = cn;
                const int jg = b * JPB + lane;
                unsigned long long pk =
                    ((unsigned long long)(unsigned)(t + 1) << 32) | __float_as_uint(hn);
                __hip_atomic_store(&pub[(size_t)((t + 1) & 1) * HID + jg], pk,
                                   __ATOMIC_RELAXED, __HIP_MEMORY_SCOPE_AGENT);
                hs[(size_t)t * HID + jg] = hn;
                if (t == SEQ - 1) { outTail[jg] = hn; outTail[HID + jg] = cn; }
            }
        }
    }
}

// ---------------------------------------------------------------------------
// K3: out[t][o] = hs[t] @ V_w[:,o] + V_b[o].
// ---------------------------------------------------------------------------
__global__ void k_out(const float* __restrict__ hs, const float* __restrict__ Vw,
                      const float* __restrict__ Vb, float* __restrict__ out) {
    __shared__ float tile[32][64];
    const int tid = threadIdx.x;
    const int t0 = blockIdx.x * 32;
    float acc[32];
#pragma unroll
    for (int r = 0; r < 32; ++r) acc[r] = 0.f;
    for (int k0 = 0; k0 < HID; k0 += 64) {
        {
            const int r = tid >> 3, kk = (tid & 7) * 8;
            const float4* p = (const float4*)(hs + (size_t)(t0 + r) * HID + k0 + kk);
            float4 a = p[0], bq = p[1];
            *(float4*)&tile[r][kk]     = a;
            *(float4*)&tile[r][kk + 4] = bq;
        }
        __syncthreads();
        for (int kk = 0; kk < 64; ++kk) {
            float w = Vw[(size_t)(k0 + kk) * ODIM + tid];
#pragma unroll
            for (int r = 0; r < 32; ++r) acc[r] += tile[r][kk] * w;
        }
        __syncthreads();
    }
    const float vb = Vb[tid];
    for (int r = 0; r < 32; ++r)
        out[(size_t)(t0 + r) * ODIM + tid] = acc[r] + vb;
}

// ---------------------------------------------------------------------------
extern "C" void kernel_launch(void* const* d_in, const int* in_sizes, int n_in,
                              void* d_out, int out_size, void* d_ws, size_t ws_size,
                              hipStream_t stream) {
    const int*   x   = (const int*)d_in[0];
    const float* emb = (const float*)d_in[1];
    const float* W[4] = {(const float*)d_in[2], (const float*)d_in[6],
                         (const float*)d_in[10], (const float*)d_in[14]};
    const float* B[4] = {(const float*)d_in[3], (const float*)d_in[7],
                         (const float*)d_in[11], (const float*)d_in[15]};
    const float* U[4] = {(const float*)d_in[4], (const float*)d_in[8],
                         (const float*)d_in[12], (const float*)d_in[16]};
    const float* C[4] = {(const float*)d_in[5], (const float*)d_in[9],
                         (const float*)d_in[13], (const float*)d_in[17]};
    const float* Vw = (const float*)d_in[18];
    const float* Vb = (const float*)d_in[19];
    float* out = (float*)d_out;

    // ws layout: Zv[256*4*2048 f32] | hs[8192*2048 f32] | pub[2*2048 ull] |
    // cnt[32 u32] | locb[8*2*2048 ull]. Poison 0xAAAAAAAA never equals a live
    // epoch (1..8192) in pub/locb; cnt is zeroed by k_init each call.
    float* ws = (float*)d_ws;
    float* Zv = ws;
    float* hs = Zv + (size_t)VOCAB * 4 * HID;
    unsigned long long* pub  = (unsigned long long*)(hs + (size_t)SEQ * HID);
    unsigned*           cnt  = (unsigned*)(pub + 2 * HID);
    unsigned long long* locb = (unsigned long long*)(cnt + 32);

    k_init<<<dim3(1), dim3(64), 0, stream>>>(cnt);
    for (int g = 0; g < 4; ++g)
        k_zv<<<dim3(8, 8), dim3(256), 0, stream>>>(emb, W[g], B[g], C[g], Zv, g);

    float* outTail = out + (size_t)SEQ * ODIM;
    const float *Ui = U[0], *Uf = U[1], *Ugp = U[2], *Uo = U[3];
    const float* Zvc = Zv; const int* xc = x;
    unsigned long long* pubc = pub; unsigned long long* locbc = locb;
    unsigned* cntc = cnt; float* hsc = hs; float* ot = outTail;
    void* args[11] = {&Ui, &Uf, &Ugp, &Uo, &Zvc, &xc, &pubc, &locbc, &cntc, &hsc, &ot};
    hipLaunchCooperativeKernel((void*)k_lstm, dim3(NBLK), dim3(NTHR), args, 0, stream);

    k_out<<<dim3(256), dim3(256), 0, stream>>>(hs, Vw, Vb, out);
}

// Round 5
// 30963.620 us; speedup vs baseline: 1.9997x; 1.2183x over previous
//
#include <hip/hip_runtime.h>

// Problem constants
#define SEQ   8192
#define VOCAB 256
#define HID   2048
#define ODIM  256
#define NBLK  256   // persistent blocks (1 per CU)
#define NTHR  512   // 8 waves per block
#define JPB   8     // hidden columns owned per block (HID/NBLK)

// Fast gate math: v_exp_f32 + v_rcp_f32 (~1ulp each; threshold is bf16-scale)
__device__ __forceinline__ float fsigmoid(float x) {
    return __builtin_amdgcn_rcpf(1.f + __expf(-x));
}
__device__ __forceinline__ float ftanh(float x) {
    x = fminf(20.f, fmaxf(-20.f, x));                 // avoid inf*0 NaN
    float e = __expf(2.f * x);
    return (e - 1.f) * __builtin_amdgcn_rcpf(e + 1.f);
}

// DPP rotate-add within 16-lane rows: after ror4 then ror8 accumulation,
// every lane holds the sum of its stride-4 group (same gate) in its row.
// Pure VALU -- frees the LDS pipe that the old ds_swizzle butterfly clogged.
__device__ __forceinline__ float dpp_ror4(float v) {
    return __int_as_float(__builtin_amdgcn_update_dpp(
        0, __float_as_int(v), 0x124, 0xF, 0xF, false));
}
__device__ __forceinline__ float dpp_ror8(float v) {
    return __int_as_float(__builtin_amdgcn_update_dpp(
        0, __float_as_int(v), 0x128, 0xF, 0xF, false));
}

// ---------------------------------------------------------------------------
// K1: Zv[v][gate][j] = emb[v] @ W_gate[:,j] + b_gate[j] + c_gate[j]
// 256 distinct x values -> whole input projection is an 8 MB lookup table.
// ---------------------------------------------------------------------------
__global__ void k_zv(const float* __restrict__ emb, const float* __restrict__ W,
                     const float* __restrict__ bb, const float* __restrict__ cb,
                     float* __restrict__ Zv, int gate) {
    __shared__ float e[32][VOCAB];
    const int tid = threadIdx.x;
    const int vt = blockIdx.x, ct = blockIdx.y;
    for (int r = 0; r < 32; ++r)
        e[r][tid] = emb[(size_t)(vt * 32 + r) * VOCAB + tid];
    __syncthreads();
    const int j = ct * 256 + tid;
    const float bias = bb[j] + cb[j];
    float acc[32];
#pragma unroll
    for (int r = 0; r < 32; ++r) acc[r] = 0.f;
    for (int u = 0; u < VOCAB; ++u) {
        float w = W[(size_t)u * HID + j];
#pragma unroll
        for (int r = 0; r < 32; ++r) acc[r] += e[r][u] * w;
    }
    for (int r = 0; r < 32; ++r)
        Zv[(size_t)(vt * 32 + r) * (4 * HID) + (size_t)gate * HID + j] = acc[r] + bias;
}

// ---------------------------------------------------------------------------
// K2: persistent cooperative LSTM. Exchange = R2's proven protocol:
// (h,epoch) 8B pairs at AGENT scope, double-buffered by parity; each thread
// spins on its own 4 pairs with s_sleep(1). New this round (pure compute-path
// streamlining):
//   - hpad staging is wave-private (group 4rs..4rs+3 stages exactly the rows
//     it consumes) -> NO pre-matvec __syncthreads, just __threadfence_block.
//     Each wave starts its matvec the moment its own producers land.
//   - DPP row_ror:4/8 rotate-adds replace the 4-stage ds_swizzle butterfly:
//     LDS-pipe traffic for the reduction drops ~4x.
//   - ONE __syncthreads per step (scr2 parity-double-buffered); wave0 reduces
//     after the barrier so waves 1-7 immediately begin step t+1's spin.
// ---------------------------------------------------------------------------
__launch_bounds__(NTHR, 2)
__global__ void k_lstm(const float* __restrict__ Uii, const float* __restrict__ Uff,
                       const float* __restrict__ Ugg, const float* __restrict__ Uoo,
                       const float* __restrict__ Zv,  const int* __restrict__ x,
                       unsigned long long* pub, float* __restrict__ hs,
                       float* __restrict__ outTail) {
    __shared__ __align__(16) float hpad[128 * 20];     // 10 KB, wave-private chunks
    __shared__ __align__(16) float scr2[2][32 * 36];   // 9 KB: parity x chunk x col(+pad)

    const int tid  = threadIdx.x;
    const int b    = blockIdx.x;
    const int gate = tid & 3;
    const int rs   = tid >> 2;              // 0..127: rows [16rs,16rs+16)
    const int lane = tid & 63;
    const int wv   = tid >> 6;

    const float* Ug = (gate == 0) ? Uii : (gate == 1) ? Uff : (gate == 2) ? Ugg : Uoo;

    // U slice -> registers (rows rs*16..+16, cols 8b..8b+8) = 128 f32/thread
    float u[16][JPB];
#pragma unroll
    for (int r = 0; r < 16; ++r) {
        const float4* p = (const float4*)(Ug + (size_t)(rs * 16 + r) * HID + b * JPB);
        float4 a0 = p[0], a1 = p[1];
        u[r][0] = a0.x; u[r][1] = a0.y; u[r][2] = a0.z; u[r][3] = a0.w;
        u[r][4] = a1.x; u[r][5] = a1.y; u[r][6] = a1.z; u[r][7] = a1.w;
    }

    float4* hp4 = (float4*)hpad;
    float creg = 0.f;                       // cell state, wave0 lanes 0-7
    unsigned budget = 1u << 22;             // watchdog: bounded spin, fails loudly

    for (int t = 0; t < SEQ; ++t) {
        // Zv prefetch (independent of h; overlaps the spin)
        float zx = 0.f;
        if (wv == 0 && lane < 32) {
            const int xt = x[t];
            zx = Zv[(size_t)xt * (4 * HID) + (size_t)(lane >> 3) * HID + b * JPB + (lane & 7)];
        }

        // --- acquire own 4 h cols [4tid,4tid+4): R2's proven pair spin ------
        float4 hv;
        if (t == 0) {
            hv = make_float4(0.f, 0.f, 0.f, 0.f);
        } else {
            const unsigned tgt = (unsigned)t;
            const unsigned long long* sl = pub + (size_t)(t & 1) * HID + tid * 4;
            unsigned long long a0, a1, a2, a3;
            for (;;) {
                a0 = __hip_atomic_load(sl + 0, __ATOMIC_RELAXED, __HIP_MEMORY_SCOPE_AGENT);
                a1 = __hip_atomic_load(sl + 1, __ATOMIC_RELAXED, __HIP_MEMORY_SCOPE_AGENT);
                a2 = __hip_atomic_load(sl + 2, __ATOMIC_RELAXED, __HIP_MEMORY_SCOPE_AGENT);
                a3 = __hip_atomic_load(sl + 3, __ATOMIC_RELAXED, __HIP_MEMORY_SCOPE_AGENT);
                if (((unsigned)(a0 >> 32) == tgt) && ((unsigned)(a1 >> 32) == tgt) &&
                    ((unsigned)(a2 >> 32) == tgt) && ((unsigned)(a3 >> 32) == tgt)) break;
                if (budget == 0) break;     // deadlock guard -> loud wrong output
                --budget;
                __builtin_amdgcn_s_sleep(1);
            }
            hv.x = __uint_as_float((unsigned)a0);
            hv.y = __uint_as_float((unsigned)a1);
            hv.z = __uint_as_float((unsigned)a2);
            hv.w = __uint_as_float((unsigned)a3);
        }

        // Stage rows [4tid,4tid+4) -> wave-private hpad region. The consuming
        // group (threads 4rs..4rs+3) is the staging group -> no block barrier,
        // only an LDS fence for intra-wave ordering.
        *(float4*)&hpad[(tid >> 2) * 20 + (tid & 3) * 4] = hv;
        __threadfence_block();

        // --- register matvec: 16 rows x 8 cols per thread ------------------
        float acc[JPB];
#pragma unroll
        for (int jj = 0; jj < JPB; ++jj) acc[jj] = 0.f;
#pragma unroll
        for (int k = 0; k < 4; ++k) {
            float4 h4 = hp4[rs * 5 + k];
            float hvv[4] = {h4.x, h4.y, h4.z, h4.w};
#pragma unroll
            for (int i = 0; i < 4; ++i)
#pragma unroll
                for (int jj = 0; jj < JPB; ++jj)
                    acc[jj] += hvv[i] * u[k * 4 + i][jj];
        }

        // --- DPP reduce: sum the 4 same-gate lanes in each 16-lane row -----
#pragma unroll
        for (int jj = 0; jj < JPB; ++jj) {
            acc[jj] += dpp_ror4(acc[jj]);
            acc[jj] += dpp_ror8(acc[jj]);
        }
        // Writers: one lane per (row, gate): lanes with (lane & 12) == 0.
        // chunk = wv*4 + row covers 64 h-rows; scr2 stride 36 keeps b128
        // alignment and conflict-free strided reads for the final sum.
        if ((lane & 12) == 0) {
            const int chunk = wv * 4 + (lane >> 4);
            float* p = &scr2[t & 1][chunk * 36 + gate * JPB];
            *(float4*)(p)     = make_float4(acc[0], acc[1], acc[2], acc[3]);
            *(float4*)(p + 4) = make_float4(acc[4], acc[5], acc[6], acc[7]);
        }
        __syncthreads();                    // the ONLY barrier per step

        // --- wave0: final reduce + gates + publish (others run ahead) ------
        if (wv == 0) {
            float z = 0.f;
            if (lane < 32) {
                const float* s = &scr2[t & 1][lane];
#pragma unroll
                for (int k = 0; k < 32; ++k) z += s[k * 36];
                z += zx;
            }
            const int jj = lane & 7;
            float zi = __shfl(z, jj);
            float zf = __shfl(z, 8 + jj);
            float zg = __shfl(z, 16 + jj);
            float zo = __shfl(z, 24 + jj);
            if (lane < JPB) {
                float ig = fsigmoid(zi);
                float fg = fsigmoid(zf);
                float gg = ftanh(zg);
                float og = fsigmoid(zo);
                float cn = fg * creg + ig * gg;
                float hn = og * ftanh(cn);
                creg = cn;
                const int jg = b * JPB + lane;
                // publish FIRST (critical path), then bulk stores
                unsigned long long pk =
                    ((unsigned long long)(unsigned)(t + 1) << 32) | __float_as_uint(hn);
                __hip_atomic_store(&pub[(size_t)((t + 1) & 1) * HID + jg], pk,
                                   __ATOMIC_RELAXED, __HIP_MEMORY_SCOPE_AGENT);
                hs[(size_t)t * HID + jg] = hn;
                if (t == SEQ - 1) { outTail[jg] = hn; outTail[HID + jg] = cn; }
            }
        }
    }
}

// ---------------------------------------------------------------------------
// K3: out[t][o] = hs[t] @ V_w[:,o] + V_b[o].
// ---------------------------------------------------------------------------
__global__ void k_out(const float* __restrict__ hs, const float* __restrict__ Vw,
                      const float* __restrict__ Vb, float* __restrict__ out) {
    __shared__ float tile[32][64];
    const int tid = threadIdx.x;
    const int t0 = blockIdx.x * 32;
    float acc[32];
#pragma unroll
    for (int r = 0; r < 32; ++r) acc[r] = 0.f;
    for (int k0 = 0; k0 < HID; k0 += 64) {
        {
            const int r = tid >> 3, kk = (tid & 7) * 8;
            const float4* p = (const float4*)(hs + (size_t)(t0 + r) * HID + k0 + kk);
            float4 a = p[0], bq = p[1];
            *(float4*)&tile[r][kk]     = a;
            *(float4*)&tile[r][kk + 4] = bq;
        }
        __syncthreads();
        for (int kk = 0; kk < 64; ++kk) {
            float w = Vw[(size_t)(k0 + kk) * ODIM + tid];
#pragma unroll
            for (int r = 0; r < 32; ++r) acc[r] += tile[r][kk] * w;
        }
        __syncthreads();
    }
    const float vb = Vb[tid];
    for (int r = 0; r < 32; ++r)
        out[(size_t)(t0 + r) * ODIM + tid] = acc[r] + vb;
}

// ---------------------------------------------------------------------------
extern "C" void kernel_launch(void* const* d_in, const int* in_sizes, int n_in,
                              void* d_out, int out_size, void* d_ws, size_t ws_size,
                              hipStream_t stream) {
    const int*   x   = (const int*)d_in[0];
    const float* emb = (const float*)d_in[1];
    const float* W[4] = {(const float*)d_in[2], (const float*)d_in[6],
                         (const float*)d_in[10], (const float*)d_in[14]};
    const float* B[4] = {(const float*)d_in[3], (const float*)d_in[7],
                         (const float*)d_in[11], (const float*)d_in[15]};
    const float* U[4] = {(const float*)d_in[4], (const float*)d_in[8],
                         (const float*)d_in[12], (const float*)d_in[16]};
    const float* C[4] = {(const float*)d_in[5], (const float*)d_in[9],
                         (const float*)d_in[13], (const float*)d_in[17]};
    const float* Vw = (const float*)d_in[18];
    const float* Vb = (const float*)d_in[19];
    float* out = (float*)d_out;

    // ws layout (floats): Zv[256*4*2048] | hs[8192*2048] | pub[2*2048 ull].
    // Poison 0xAAAAAAAA never equals a live epoch (1..8192), and ws is
    // re-poisoned before every timed call -> no init kernel needed.
    float* ws = (float*)d_ws;
    float* Zv = ws;
    float* hs = Zv + (size_t)VOCAB * 4 * HID;
    unsigned long long* pub = (unsigned long long*)(hs + (size_t)SEQ * HID);

    for (int g = 0; g < 4; ++g)
        k_zv<<<dim3(8, 8), dim3(256), 0, stream>>>(emb, W[g], B[g], C[g], Zv, g);

    float* outTail = out + (size_t)SEQ * ODIM;
    const float *Ui = U[0], *Uf = U[1], *Ugp = U[2], *Uo = U[3];
    const float* Zvc = Zv; const int* xc = x;
    unsigned long long* pubc = pub; float* hsc = hs; float* ot = outTail;
    void* args[9] = {&Ui, &Uf, &Ugp, &Uo, &Zvc, &xc, &pubc, &hsc, &ot};
    hipLaunchCooperativeKernel((void*)k_lstm, dim3(NBLK), dim3(NTHR), args, 0, stream);

    k_out<<<dim3(256), dim3(256), 0, stream>>>(hs, Vw, Vb, out);
}

// Round 9
// 17557.292 us; speedup vs baseline: 3.5267x; 1.7636x over previous
//
#include <hip/hip_runtime.h>

// Problem constants
#define SEQ   8192
#define VOCAB 256
#define HID   2048
#define ODIM  256
#define NBLK  256   // persistent blocks (1 per CU)
#define NTHR  512   // 8 waves per block
#define JPB   8     // hidden columns owned per block (HID/NBLK)

typedef unsigned int v4u __attribute__((ext_vector_type(4)));

// Read this thread's 4 (h,epoch32) fp32 pairs (32 B) as two coherent dwordx4
// with the drain INSIDE the asm block: no load is ever in flight when control
// leaves the block (R8's async-clobber bug is structurally impossible).
// sc0 sc1 = bypass L1/L2, read the device coherence point.
__device__ __forceinline__ void ld32_coh_sync(const void* p, v4u& r0, v4u& r1) {
    asm volatile("global_load_dwordx4 %0, %2, off sc0 sc1\n\t"
                 "global_load_dwordx4 %1, %2, off offset:16 sc0 sc1\n\t"
                 "s_waitcnt vmcnt(0)"
                 : "=&v"(r0), "=&v"(r1) : "v"(p) : "memory");
}

// Fast gate math: v_exp_f32 + v_rcp_f32 (~1ulp each)
__device__ __forceinline__ float fsigmoid(float x) {
    return __builtin_amdgcn_rcpf(1.f + __expf(-x));
}
__device__ __forceinline__ float ftanh(float x) {
    x = fminf(20.f, fmaxf(-20.f, x));                 // avoid inf*0 NaN
    float e = __expf(2.f * x);
    return (e - 1.f) * __builtin_amdgcn_rcpf(e + 1.f);
}

// DPP rotate-add within 16-lane rows: ror4 + ror8 -> every lane holds the sum
// of its stride-4 (same-gate) group. Pure VALU, LDS pipe stays free.
__device__ __forceinline__ float dpp_ror4(float v) {
    return __int_as_float(__builtin_amdgcn_update_dpp(
        0, __float_as_int(v), 0x124, 0xF, 0xF, false));
}
__device__ __forceinline__ float dpp_ror8(float v) {
    return __int_as_float(__builtin_amdgcn_update_dpp(
        0, __float_as_int(v), 0x128, 0xF, 0xF, false));
}

// ---------------------------------------------------------------------------
// K1: Zv[v][gate][j] = emb[v] @ W_gate[:,j] + b_gate[j] + c_gate[j]
// 256 distinct x values -> whole input projection is an 8 MB lookup table.
// ---------------------------------------------------------------------------
__global__ void k_zv(const float* __restrict__ emb, const float* __restrict__ W,
                     const float* __restrict__ bb, const float* __restrict__ cb,
                     float* __restrict__ Zv, int gate) {
    __shared__ float e[32][VOCAB];
    const int tid = threadIdx.x;
    const int vt = blockIdx.x, ct = blockIdx.y;
    for (int r = 0; r < 32; ++r)
        e[r][tid] = emb[(size_t)(vt * 32 + r) * VOCAB + tid];
    __syncthreads();
    const int j = ct * 256 + tid;
    const float bias = bb[j] + cb[j];
    float acc[32];
#pragma unroll
    for (int r = 0; r < 32; ++r) acc[r] = 0.f;
    for (int u = 0; u < VOCAB; ++u) {
        float w = W[(size_t)u * HID + j];
#pragma unroll
        for (int r = 0; r < 32; ++r) acc[r] += e[r][u] * w;
    }
    for (int r = 0; r < 32; ++r)
        Zv[(size_t)(vt * 32 + r) * (4 * HID) + (size_t)gate * HID + j] = acc[r] + bias;
}

// ---------------------------------------------------------------------------
// K2: persistent cooperative LSTM.
// Exchange: fp32 (h, epoch32) 8-B pairs at AGENT scope, double-buffered by
// step parity. BIT-EXACT h (R6/R7: amplification ~1.5e4 makes any lossy
// exchange diverge past threshold; fp32 reorder noise stays sub-floor).
// Poll: self-draining 32-B sample (2 requests) + s_sleep(1) -- R5-proven
// protocol shape, half the request count.
// Compute: U register-resident (128 f32/thread), wave-private hpad (no
// pre-matvec barrier), DPP reduce, ONE barrier/step.
// Tail: distributed -- wave wv owns hidden column b*8+wv (2 LDS reads +
// xor-tree + gates redundant in all lanes), lane 0 publishes.
// ---------------------------------------------------------------------------
__launch_bounds__(NTHR, 2)
__global__ void k_lstm(const float* __restrict__ Uii, const float* __restrict__ Uff,
                       const float* __restrict__ Ugg, const float* __restrict__ Uoo,
                       const float* __restrict__ Zv,  const int* __restrict__ x,
                       unsigned long long* pub, float* __restrict__ hs,
                       float* __restrict__ outTail) {
    __shared__ __align__(16) float hpad[128 * 20];     // 10 KB, wave-private chunks
    __shared__ __align__(16) float scr2[2][32 * 36];   // 9 KB: parity x chunk x col(+pad)

    const int tid  = threadIdx.x;
    const int b    = blockIdx.x;
    const int gate = tid & 3;
    const int rs   = tid >> 2;              // 0..127: rows [16rs,16rs+16)
    const int lane = tid & 63;
    const int wv   = tid >> 6;
    const int jg   = b * JPB + wv;          // hidden column this WAVE owns

    const float* Ug = (gate == 0) ? Uii : (gate == 1) ? Uff : (gate == 2) ? Ugg : Uoo;

    // U slice -> registers (rows rs*16..+16, cols 8b..8b+8) = 128 f32/thread
    float u[16][JPB];
#pragma unroll
    for (int r = 0; r < 16; ++r) {
        const float4* p = (const float4*)(Ug + (size_t)(rs * 16 + r) * HID + b * JPB);
        float4 a0 = p[0], a1 = p[1];
        u[r][0] = a0.x; u[r][1] = a0.y; u[r][2] = a0.z; u[r][3] = a0.w;
        u[r][4] = a1.x; u[r][5] = a1.y; u[r][6] = a1.z; u[r][7] = a1.w;
    }

    float4* hp4 = (float4*)hpad;
    float creg = 0.f;                       // col-jg cell state (all lanes identical)
    unsigned budget = 1u << 22;             // watchdog: bounded spin, fails loudly

    for (int t = 0; t < SEQ; ++t) {
        // Zv prefetch: this lane's gate bias for column jg (uniform per
        // gate-class; issued before the poll so it overlaps the spin)
        const int xt = x[t];
        float zx = Zv[(size_t)xt * (4 * HID) + (size_t)gate * HID + jg];

        // --- acquire own 4 h cols [4tid,4tid+4): self-draining poll --------
        float4 hv;
        if (t == 0) {
            hv = make_float4(0.f, 0.f, 0.f, 0.f);
        } else {
            const unsigned tgt = (unsigned)t;
            const unsigned long long* sl = pub + (size_t)(t & 1) * HID + tid * 4;
            v4u A0, A1;
            for (;;) {
                ld32_coh_sync(sl, A0, A1);  // 2 requests, drained in-block
                if (((A0.y == tgt) & (A0.w == tgt) &
                     (A1.y == tgt) & (A1.w == tgt)) || budget == 0) break;
                --budget;
                __builtin_amdgcn_s_sleep(1);
            }
            hv.x = __uint_as_float(A0.x);   // pair = (h lo-word, epoch hi-word)
            hv.y = __uint_as_float(A0.z);
            hv.z = __uint_as_float(A1.x);
            hv.w = __uint_as_float(A1.z);
        }

        // Stage rows [4tid,4tid+4) -> wave-private hpad region (consuming
        // group == staging group) -> no block barrier, just an LDS fence.
        *(float4*)&hpad[(tid >> 2) * 20 + (tid & 3) * 4] = hv;
        __threadfence_block();

        // --- register matvec: 16 rows x 8 cols per thread ------------------
        float acc[JPB];
#pragma unroll
        for (int jj = 0; jj < JPB; ++jj) acc[jj] = 0.f;
#pragma unroll
        for (int k = 0; k < 4; ++k) {
            float4 h4 = hp4[rs * 5 + k];
            float hvv[4] = {h4.x, h4.y, h4.z, h4.w};
#pragma unroll
            for (int i = 0; i < 4; ++i)
#pragma unroll
                for (int jj = 0; jj < JPB; ++jj)
                    acc[jj] += hvv[i] * u[k * 4 + i][jj];
        }

        // --- DPP reduce: sum the 4 same-gate lanes in each 16-lane row -----
#pragma unroll
        for (int jj = 0; jj < JPB; ++jj) {
            acc[jj] += dpp_ror4(acc[jj]);
            acc[jj] += dpp_ror8(acc[jj]);
        }
        if ((lane & 12) == 0) {             // one writer per (row, gate)
            const int chunk = wv * 4 + (lane >> 4);
            float* p = &scr2[t & 1][chunk * 36 + gate * JPB];
            *(float4*)(p)     = make_float4(acc[0], acc[1], acc[2], acc[3]);
            *(float4*)(p + 4) = make_float4(acc[4], acc[5], acc[6], acc[7]);
        }
        __syncthreads();                    // the ONLY barrier per step

        // --- distributed tail: this wave finishes column jg ----------------
        {
            const int c = lane >> 2;        // 0..15
            const float* s = &scr2[t & 1][0];
            float z = s[c * 36 + gate * JPB + wv] +
                      s[(c + 16) * 36 + gate * JPB + wv];
            z += __shfl_xor(z, 4);          // xor-tree over bits 2..5:
            z += __shfl_xor(z, 8);          //   every lane -> total for its gate
            z += __shfl_xor(z, 16);
            z += __shfl_xor(z, 32);
            z += zx;                        // gate bias (uniform per gate-class)
            float zi = __shfl(z, 0);
            float zf = __shfl(z, 1);
            float zg = __shfl(z, 2);
            float zo = __shfl(z, 3);
            // gates computed redundantly in all lanes (uniform, no divergence)
            float ig = fsigmoid(zi);
            float fg = fsigmoid(zf);
            float gg = ftanh(zg);
            float og = fsigmoid(zo);
            float cn = fg * creg + ig * gg;
            float hn = og * ftanh(cn);
            creg = cn;
            if (lane == 0) {
                // publish FIRST (critical path)
                unsigned long long pk =
                    ((unsigned long long)(unsigned)(t + 1) << 32) | __float_as_uint(hn);
                __hip_atomic_store(&pub[(size_t)((t + 1) & 1) * HID + jg], pk,
                                   __ATOMIC_RELAXED, __HIP_MEMORY_SCOPE_AGENT);
                hs[(size_t)t * HID + jg] = hn;
                if (t == SEQ - 1) { outTail[jg] = hn; outTail[HID + jg] = cn; }
            }
        }
    }
}

// ---------------------------------------------------------------------------
// K3: out[t][o] = hs[t] @ V_w[:,o] + V_b[o].
// ---------------------------------------------------------------------------
__global__ void k_out(const float* __restrict__ hs, const float* __restrict__ Vw,
                      const float* __restrict__ Vb, float* __restrict__ out) {
    __shared__ float tile[32][64];
    const int tid = threadIdx.x;
    const int t0 = blockIdx.x * 32;
    float acc[32];
#pragma unroll
    for (int r = 0; r < 32; ++r) acc[r] = 0.f;
    for (int k0 = 0; k0 < HID; k0 += 64) {
        {
            const int r = tid >> 3, kk = (tid & 7) * 8;
            const float4* p = (const float4*)(hs + (size_t)(t0 + r) * HID + k0 + kk);
            float4 a = p[0], bq = p[1];
            *(float4*)&tile[r][kk]     = a;
            *(float4*)&tile[r][kk + 4] = bq;
        }
        __syncthreads();
        for (int kk = 0; kk < 64; ++kk) {
            float w = Vw[(size_t)(k0 + kk) * ODIM + tid];
#pragma unroll
            for (int r = 0; r < 32; ++r) acc[r] += tile[r][kk] * w;
        }
        __syncthreads();
    }
    const float vb = Vb[tid];
    for (int r = 0; r < 32; ++r)
        out[(size_t)(t0 + r) * ODIM + tid] = acc[r] + vb;
}

// ---------------------------------------------------------------------------
extern "C" void kernel_launch(void* const* d_in, const int* in_sizes, int n_in,
                              void* d_out, int out_size, void* d_ws, size_t ws_size,
                              hipStream_t stream) {
    const int*   x   = (const int*)d_in[0];
    const float* emb = (const float*)d_in[1];
    const float* W[4] = {(const float*)d_in[2], (const float*)d_in[6],
                         (const float*)d_in[10], (const float*)d_in[14]};
    const float* B[4] = {(const float*)d_in[3], (const float*)d_in[7],
                         (const float*)d_in[11], (const float*)d_in[15]};
    const float* U[4] = {(const float*)d_in[4], (const float*)d_in[8],
                         (const float*)d_in[12], (const float*)d_in[16]};
    const float* C[4] = {(const float*)d_in[5], (const float*)d_in[9],
                         (const float*)d_in[13], (const float*)d_in[17]};
    const float* Vw = (const float*)d_in[18];
    const float* Vb = (const float*)d_in[19];
    float* out = (float*)d_out;

    // ws layout (floats): Zv[256*4*2048] | hs[8192*2048] | pub[2*2048 ull].
    // Poison epoch word 0xAAAAAAAA never equals a live epoch (1..8192), and
    // ws is re-poisoned before every timed call -> no init kernel needed.
    float* ws = (float*)d_ws;
    float* Zv = ws;
    float* hs = Zv + (size_t)VOCAB * 4 * HID;
    unsigned long long* pub = (unsigned long long*)(hs + (size_t)SEQ * HID);

    for (int g = 0; g < 4; ++g)
        k_zv<<<dim3(8, 8), dim3(256), 0, stream>>>(emb, W[g], B[g], C[g], Zv, g);

    float* outTail = out + (size_t)SEQ * ODIM;
    const float *Ui = U[0], *Uf = U[1], *Ugp = U[2], *Uo = U[3];
    const float* Zvc = Zv; const int* xc = x;
    unsigned long long* pubc = pub; float* hsc = hs; float* ot = outTail;
    void* args[9] = {&Ui, &Uf, &Ugp, &Uo, &Zvc, &xc, &pubc, &hsc, &ot};
    hipLaunchCooperativeKernel((void*)k_lstm, dim3(NBLK), dim3(NTHR), args, 0, stream);

    k_out<<<dim3(256), dim3(256), 0, stream>>>(hs, Vw, Vb, out);
}